// Round 1
// baseline (3172.657 us; speedup 1.0000x reference)
//
#include <hip/hip_runtime.h>
#include <hip/hip_fp16.h>

namespace {

constexpr int kS  = 1024;   // SEQ
constexpr int kI  = 64;     // INPUT_SIZE
constexpr int kH  = 128;    // HIDDEN
constexpr int kG  = 512;    // 4*HIDDEN
constexpr int kTB1 = 64;    // x staging block (steps)
constexpr int kTB2 = 32;    // h1 staging block (steps)

typedef _Float16 h2v __attribute__((ext_vector_type(2)));

__device__ __forceinline__ float dot2(__half2 a, __half2 b, float c) {
#if __has_builtin(__builtin_amdgcn_fdot2)
  h2v av = __builtin_bit_cast(h2v, a);
  h2v bv = __builtin_bit_cast(h2v, b);
  return __builtin_amdgcn_fdot2(av, bv, c, false);
#else
  c = fmaf(__half2float(__low2half(a)),  __half2float(__low2half(b)),  c);
  c = fmaf(__half2float(__high2half(a)), __half2float(__high2half(b)), c);
  return c;
#endif
}

__device__ __forceinline__ float sigf(float x) { return 1.0f / (1.0f + __expf(-x)); }

// ---------------- Layer 1: fused input projection + recurrence ----------------
// 256 blocks x 512 threads. Block handles chains b0, b0+1. Thread tid owns gate
// row r=tid of Wx1 (64 wts) and Wh1 (128 wts) in VGPRs as packed __half2.
__global__ __launch_bounds__(512) void lstm_l1(
    const float* __restrict__ x, const float* __restrict__ Wx1,
    const float* __restrict__ bx1, const float* __restrict__ Wh1,
    const float* __restrict__ bh1, __half* __restrict__ h1out)
{
  const int tid = threadIdx.x;
  const int b0  = blockIdx.x * 2;

  __shared__ __align__(16) __half2 xs[kTB1][2][kI/2];   // 16 KiB staged x (fp16)
  __shared__ __align__(16) __half2 hbuf[2][2][kH/2];    // 1 KiB double-buffered h
  __shared__ float gbuf[2][kG];                         // 4 KiB gate preacts

  // --- load weights for row r = tid into registers (packed fp16) ---
  __half2 wx[kI/2];
  __half2 wh[kH/2];
  {
    const float* p = Wx1 + tid * kI;
#pragma unroll
    for (int i = 0; i < kI/2; ++i) wx[i] = __floats2half2_rn(p[2*i], p[2*i+1]);
    const float* q = Wh1 + tid * kH;
#pragma unroll
    for (int i = 0; i < kH/2; ++i) wh[i] = __floats2half2_rn(q[2*i], q[2*i+1]);
  }
  const float bias = bx1[tid] + bh1[tid];

  // init h buffers (both) to zero
  if (tid < 256) reinterpret_cast<__half2*>(hbuf)[tid] = __float2half2_rn(0.0f);
  float cst = 0.0f;                       // cell state for (j, cc), tid < 256
  const int j = tid & 127, cc = tid >> 7;

  for (int t0 = 0; t0 < kS; t0 += kTB1) {
    __syncthreads();  // xs free to overwrite; also publishes hbuf init on iter 0
    // stage x[b0..b0+1][t0..t0+63][0..63] -> fp16 in LDS (2048 float4 loads)
#pragma unroll
    for (int q4 = 0; q4 < 4; ++q4) {
      const int idx = q4 * 512 + tid;     // float4 index 0..2047
      const int c   = idx >> 10;
      const int rem = idx & 1023;
      const int dt  = rem >> 4;
      const int i4  = rem & 15;
      const float4 v = *reinterpret_cast<const float4*>(
          x + ((size_t)(b0 + c) * kS + (size_t)(t0 + dt)) * kI + i4 * 4);
      xs[dt][c][i4*2]   = __floats2half2_rn(v.x, v.y);
      xs[dt][c][i4*2+1] = __floats2half2_rn(v.z, v.w);
    }
    __syncthreads();

    for (int dt = 0; dt < kTB1; ++dt) {
      const int t = t0 + dt;
      const int cur = t & 1, nxt = cur ^ 1;
      // gate preactivation for row tid, chains 0/1; 4 acc chains for ILP
      float a0 = bias, a1 = bias, a0b = 0.0f, a1b = 0.0f;
#pragma unroll
      for (int p = 0; p < kI/2; p += 2) {
        a0  = dot2(wx[p],   xs[dt][0][p],   a0);
        a1  = dot2(wx[p],   xs[dt][1][p],   a1);
        a0b = dot2(wx[p+1], xs[dt][0][p+1], a0b);
        a1b = dot2(wx[p+1], xs[dt][1][p+1], a1b);
      }
#pragma unroll
      for (int p = 0; p < kH/2; p += 2) {
        a0  = dot2(wh[p],   hbuf[cur][0][p],   a0);
        a1  = dot2(wh[p],   hbuf[cur][1][p],   a1);
        a0b = dot2(wh[p+1], hbuf[cur][0][p+1], a0b);
        a1b = dot2(wh[p+1], hbuf[cur][1][p+1], a1b);
      }
      gbuf[0][tid] = a0 + a0b;
      gbuf[1][tid] = a1 + a1b;
      __syncthreads();
      if (tid < 256) {
        const float gi = gbuf[cc][j];
        const float gf = gbuf[cc][j + 128];
        const float gg = gbuf[cc][j + 256];
        const float go = gbuf[cc][j + 384];
        cst = sigf(gf) * cst + sigf(gi) * tanhf(gg);
        const float h = sigf(go) * tanhf(cst);
        const __half hh = __float2half_rn(h);
        reinterpret_cast<__half*>(&hbuf[nxt][cc][0])[j] = hh;
        h1out[((size_t)(b0 + cc) * kS + (size_t)t) * kH + j] = hh;
      }
      __syncthreads();
    }
  }
}

// ------------- Layer 2: fused h1 projection + recurrence + classifier --------
__global__ __launch_bounds__(512) void lstm_l2(
    const __half* __restrict__ h1in, const float* __restrict__ Wx2,
    const float* __restrict__ bx2, const float* __restrict__ Wh2,
    const float* __restrict__ bh2, const float* __restrict__ Wc,
    const float* __restrict__ bc, float* __restrict__ out)
{
  const int tid = threadIdx.x;
  const int b0  = blockIdx.x * 2;

  __shared__ __align__(16) __half2 hs[kTB2][2][kH/2];   // 16 KiB staged h1
  __shared__ __align__(16) __half2 hbuf[2][2][kH/2];    // 1 KiB h2 double buffer
  __shared__ float gbuf[2][kG];                         // 4 KiB
  __shared__ float hfin[2][kH];                         // final h2 (fp32)

  __half2 wx[kH/2];
  __half2 wh[kH/2];
  {
    const float* p = Wx2 + tid * kH;
#pragma unroll
    for (int i = 0; i < kH/2; ++i) wx[i] = __floats2half2_rn(p[2*i], p[2*i+1]);
    const float* q = Wh2 + tid * kH;
#pragma unroll
    for (int i = 0; i < kH/2; ++i) wh[i] = __floats2half2_rn(q[2*i], q[2*i+1]);
  }
  const float bias = bx2[tid] + bh2[tid];

  if (tid < 256) reinterpret_cast<__half2*>(hbuf)[tid] = __float2half2_rn(0.0f);
  float cst = 0.0f;
  const int j = tid & 127, cc = tid >> 7;

  for (int t0 = 0; t0 < kS; t0 += kTB2) {
    __syncthreads();
    // stage h1[b0..b0+1][t0..t0+31][:] (already fp16): 1024 uint4 loads
#pragma unroll
    for (int q4 = 0; q4 < 2; ++q4) {
      const int idx = q4 * 512 + tid;     // uint4 index 0..1023
      const int c   = idx >> 9;
      const int rem = idx & 511;
      const int dt  = rem >> 4;
      const int p4  = rem & 15;
      const uint4* src = reinterpret_cast<const uint4*>(
          h1in + ((size_t)(b0 + c) * kS + (size_t)(t0 + dt)) * kH);
      *(reinterpret_cast<uint4*>(&hs[dt][c][0]) + p4) = src[p4];
    }
    __syncthreads();

    for (int dt = 0; dt < kTB2; ++dt) {
      const int t = t0 + dt;
      const int cur = t & 1, nxt = cur ^ 1;
      float a0 = bias, a1 = bias, a0b = 0.0f, a1b = 0.0f;
#pragma unroll
      for (int p = 0; p < kH/2; p += 2) {
        a0  = dot2(wx[p],   hs[dt][0][p],   a0);
        a1  = dot2(wx[p],   hs[dt][1][p],   a1);
        a0b = dot2(wx[p+1], hs[dt][0][p+1], a0b);
        a1b = dot2(wx[p+1], hs[dt][1][p+1], a1b);
      }
#pragma unroll
      for (int p = 0; p < kH/2; p += 2) {
        a0  = dot2(wh[p],   hbuf[cur][0][p],   a0);
        a1  = dot2(wh[p],   hbuf[cur][1][p],   a1);
        a0b = dot2(wh[p+1], hbuf[cur][0][p+1], a0b);
        a1b = dot2(wh[p+1], hbuf[cur][1][p+1], a1b);
      }
      gbuf[0][tid] = a0 + a0b;
      gbuf[1][tid] = a1 + a1b;
      __syncthreads();
      if (tid < 256) {
        const float gi = gbuf[cc][j];
        const float gf = gbuf[cc][j + 128];
        const float gg = gbuf[cc][j + 256];
        const float go = gbuf[cc][j + 384];
        cst = sigf(gf) * cst + sigf(gi) * tanhf(gg);
        const float h = sigf(go) * tanhf(cst);
        reinterpret_cast<__half*>(&hbuf[nxt][cc][0])[j] = __float2half_rn(h);
        if (t == kS - 1) hfin[cc][j] = h;   // keep fp32 h2 for the head
      }
      __syncthreads();
    }
  }

  // classifier head: logits[b, n] = Wc[n,:] . h2[b,:] + bc[n]
  if (tid < 8) {
    const int n = tid & 3, c = tid >> 2;
    float acc = bc[n];
    const float* wr = Wc + n * kH;
    float s0 = 0.f, s1 = 0.f, s2 = 0.f, s3 = 0.f;
#pragma unroll
    for (int jj = 0; jj < kH; jj += 4) {
      s0 = fmaf(wr[jj+0], hfin[c][jj+0], s0);
      s1 = fmaf(wr[jj+1], hfin[c][jj+1], s1);
      s2 = fmaf(wr[jj+2], hfin[c][jj+2], s2);
      s3 = fmaf(wr[jj+3], hfin[c][jj+3], s3);
    }
    out[(size_t)(b0 + c) * 4 + n] = acc + ((s0 + s1) + (s2 + s3));
  }
}

} // namespace

extern "C" void kernel_launch(void* const* d_in, const int* in_sizes, int n_in,
                              void* d_out, int out_size, void* d_ws, size_t ws_size,
                              hipStream_t stream) {
  const float* x   = (const float*)d_in[0];
  const float* Wx1 = (const float*)d_in[1];
  const float* bx1 = (const float*)d_in[2];
  const float* Wh1 = (const float*)d_in[3];
  const float* bh1 = (const float*)d_in[4];
  const float* Wx2 = (const float*)d_in[5];
  const float* bx2 = (const float*)d_in[6];
  const float* Wh2 = (const float*)d_in[7];
  const float* bh2 = (const float*)d_in[8];
  const float* Wc  = (const float*)d_in[9];
  const float* bc  = (const float*)d_in[10];

  __half* h1 = (__half*)d_ws;  // 512*1024*128 fp16 = 128 MiB stream of layer-1 h

  hipLaunchKernelGGL(lstm_l1, dim3(256), dim3(512), 0, stream,
                     x, Wx1, bx1, Wh1, bh1, h1);
  hipLaunchKernelGGL(lstm_l2, dim3(256), dim3(512), 0, stream,
                     h1, Wx2, bx2, Wh2, bh2, Wc, bc, (float*)d_out);
}